// Round 9
// baseline (72.515 us; speedup 1.0000x reference)
//
#include <hip/hip_runtime.h>
#include <hip/hip_bf16.h>

// NCE / NT-Xent loss, B=4096, D=256, temp=0.5.
// loss = mean_i( log(sum_{j!=i} exp(sim_ij)) - sim_{i,(i+B)%N} ), N=8192.
// |sim| <= 1/temp = 2 => exp(sim) <= e^2: no online max needed, plain sum(exp).
//
// Zn stored scaled by sqrt(2*log2(e)) so MFMA output is the exp2 argument.
// Fragment-tiled Zn layout: 16-row group g is an 8KB contiguous block;
// lane l's fragment ks of group g = contiguous 16B at zn + g*4096 + ks*512 + l*8.
//
// R9: stage-once / free-run. Each block stages its whole 64KB B half-panel
// (8 column groups) into LDS with ONE vmcnt(0)+barrier, then 8 waves run the
// tile loop barrier-free (desynchronized) so MFMA/VALU/LDS pipes overlap
// across waves. 512-thread blocks, 2 blocks/CU (4 waves/SIMD).

constexpr int kN  = 8192;        // 2B rows
constexpr int kD  = 256;         // embedding dim
constexpr int kBH = 4096;        // B
constexpr int kColsBlk = 128;    // columns per block (LDS panel = 64KB)
constexpr int kBlkCol  = kN / kColsBlk;   // 64 column blocks
constexpr int kNT = kColsBlk / 16;        // 8 B-tiles per panel
constexpr float kSqrtScale = 1.6986436f;  // sqrt(2*log2(e))
constexpr float kLn2 = 0.6931471805599453f;

typedef __attribute__((ext_vector_type(8))) short bf16x8;  // 8 bf16 = 4 VGPRs
typedef __attribute__((ext_vector_type(4))) float f32x4;

__device__ __forceinline__ unsigned short f2bf(float f) {
  union { float f; unsigned u; } x;
  x.f = f;
  unsigned u = x.u;
  return (unsigned short)((u + 0x7FFFu + ((u >> 16) & 1u)) >> 16);
}

__device__ __forceinline__ void gload_lds16(const short* g, short* l) {
  __builtin_amdgcn_global_load_lds(
      (const __attribute__((address_space(1))) void*)g,
      (__attribute__((address_space(3))) void*)l, 16, 0, 0);
}

// ---------------- kernel 1: row-normalize fp32 -> bf16 (tiled + scaled) ---
__global__ void k_normalize(const float* __restrict__ e1,
                            const float* __restrict__ e2,
                            unsigned short* __restrict__ zn,
                            float* __restrict__ accum /* 2*kN floats */) {
  if (blockIdx.x < 16) {
    float4 z4 = {0.f, 0.f, 0.f, 0.f};
    *reinterpret_cast<float4*>(accum + blockIdx.x * 1024 + threadIdx.x * 4) = z4;
  }
  const int wave = threadIdx.x >> 6;
  const int lane = threadIdx.x & 63;
  const int row  = blockIdx.x * 4 + wave;
  const float* src = (row < kBH) ? (e1 + (size_t)row * kD)
                                 : (e2 + (size_t)(row - kBH) * kD);
  float4 v = *reinterpret_cast<const float4*>(src + lane * 4);
  float ssq = v.x * v.x + v.y * v.y + v.z * v.z + v.w * v.w;
#pragma unroll
  for (int m = 1; m < 64; m <<= 1) ssq += __shfl_xor(ssq, m);
  const float invs = kSqrtScale / sqrtf(ssq);   // eps can never bind (|z|~16)
  ushort4 o;
  o.x = f2bf(v.x * invs);
  o.y = f2bf(v.y * invs);
  o.z = f2bf(v.z * invs);
  o.w = f2bf(v.w * invs);
  // lane holds dims 4*lane..4*lane+3 -> ks=lane>>3, lhi=(lane>>1)&3, dlo=(lane&1)*4
  const int g  = row >> 4;
  const int rr = row & 15;
  const size_t dst = (size_t)g * 4096 + (lane >> 3) * 512 +
                     ((lane >> 1) & 3) * 128 + rr * 8 + (lane & 1) * 4;
  *reinterpret_cast<ushort4*>(zn + dst) = o;
}

// ---------------- kernel 2: fused Z.Z^T + per-row sum(exp) ----------------
// Grid: 32 row-tiles (256 rows) x 64 col-blocks (128 cols) = 2048 blocks.
// Block: 8 waves x 32 rows (two 16-row MFMA subtiles each). B half-panel
// (8 groups x 8KB = 64KB) staged once into LDS; single barrier; then the
// tile loop is barrier-free and waves free-run.
__global__ __launch_bounds__(512, 4)
void k_simlse(const unsigned short* __restrict__ zn,
              float* __restrict__ s_sum,
              float* __restrict__ pos_sum) {
  __shared__ __align__(16) short ldsB[kNT * 4096];   // 64KB

  const int bid = blockIdx.x;
  const int rt  = bid >> 6;   // row tile 0..31 (256 rows each)
  const int ch  = bid & 63;   // column block 0..63 (fast -> XCD L2 spread)
  const int tid = threadIdx.x;
  const int wave = tid >> 6;
  const int lane = tid & 63;
  const int l15 = lane & 15;
  const int lhi = lane >> 4;
  const int rowBase = rt * 256 + wave * 32;
  const int colBase = ch * kColsBlk;

  // ---- stage the whole 64KB B panel (8 groups, contiguous in zn) ----
  {
    const short* src = (const short*)zn + (size_t)(colBase >> 4) * 4096;
#pragma unroll
    for (int r = 0; r < 8; ++r)
      gload_lds16(src + r * 4096 + tid * 8, &ldsB[r * 4096 + tid * 8]);
  }

  // ---- A fragments (2 groups = 32 rows), issued while stage in flight ----
  bf16x8 a0[8], a1[8];
  {
    const unsigned short* ap = zn + (size_t)(rowBase >> 4) * 4096 + lane * 8;
#pragma unroll
    for (int ks = 0; ks < 8; ++ks) {
      a0[ks] = *reinterpret_cast<const bf16x8*>(ap + ks * 512);
      a1[ks] = *reinterpret_cast<const bf16x8*>(ap + 4096 + ks * 512);
    }
  }

  float sacc[2][4] = {{0.f,0.f,0.f,0.f},{0.f,0.f,0.f,0.f}};
  float pacc[2][4] = {{0.f,0.f,0.f,0.f},{0.f,0.f,0.f,0.f}};

  asm volatile("s_waitcnt vmcnt(0)" ::: "memory");
  __builtin_amdgcn_s_barrier();

  // ---- barrier-free tile loop: 8 tiles of 16 columns from LDS ----
#pragma unroll 1
  for (int t = 0; t < kNT; ++t) {
    const short* bt = &ldsB[t * 4096];
    bf16x8 b[8];
#pragma unroll
    for (int ks = 0; ks < 8; ++ks)
      b[ks] = *reinterpret_cast<const bf16x8*>(bt + ks * 512 + lane * 8);

    f32x4 acc0 = {0.f,0.f,0.f,0.f};
    f32x4 acc1 = {0.f,0.f,0.f,0.f};
#pragma unroll
    for (int ks = 0; ks < 8; ++ks) {
      acc0 = __builtin_amdgcn_mfma_f32_16x16x32_bf16(a0[ks], b[ks], acc0, 0, 0, 0);
      acc1 = __builtin_amdgcn_mfma_f32_16x16x32_bf16(a1[ks], b[ks], acc1, 0, 0, 0);
    }

    const int cb = colBase + t * 16;
    const int c  = cb + l15;   // C/D layout: col = lane&15
#pragma unroll
    for (int s = 0; s < 2; ++s) {
      const f32x4 acc = s ? acc1 : acc0;
      const int rbase16 = rowBase + s * 16;
      const bool diagT = (cb == rbase16);                       // wave-uniform
      const bool posT  = (cb == ((rbase16 + kBH) & (kN - 1)));  // wave-uniform
      if (!diagT && !posT) {
#pragma unroll
        for (int j = 0; j < 4; ++j)
          sacc[s][j] += exp2f(acc[j]);     // acc already = sim/temp*log2(e)
      } else {
#pragma unroll
        for (int j = 0; j < 4; ++j) {
          const int row = rbase16 + lhi * 4 + j;  // C/D: row=(lane>>4)*4+j
          const float v = acc[j] * kLn2;          // sim/temp
          float p = exp2f(acc[j]);
          if (diagT && c == row) p = 0.0f;                       // mask diag
          if (posT && c == ((row + kBH) & (kN - 1))) pacc[s][j] += v;
          sacc[s][j] += p;
        }
      }
    }
  }

  // ---- fold across the 16-lane column group; l15==0 lanes own rows ----
#pragma unroll
  for (int s = 0; s < 2; ++s) {
    const int rbase16 = rowBase + s * 16;
    const int pc = (rbase16 + kBH) & (kN - 1);
    const bool hasPos = (pc >= colBase) && (pc < colBase + kColsBlk);
#pragma unroll
    for (int j = 0; j < 4; ++j) {
      float sv = sacc[s][j];
      float pv = pacc[s][j];
#pragma unroll
      for (int m = 1; m < 16; m <<= 1) {
        sv += __shfl_xor(sv, m);
        pv += __shfl_xor(pv, m);
      }
      if (l15 == 0) {
        const int row = rbase16 + lhi * 4 + j;
        atomicAdd(&s_sum[row], sv);
        if (hasPos) atomicAdd(&pos_sum[row], pv);
      }
    }
  }
}

// ---------------- kernel 3: log, subtract pos, final reduce ---------------
__global__ void k_final(const float* __restrict__ s_sum,
                        const float* __restrict__ pos_sum,
                        float* __restrict__ out) {
  __shared__ float red[16];
  float acc = 0.0f;
  for (int r = threadIdx.x; r < kN; r += 1024)
    acc += logf(s_sum[r]) - pos_sum[r];
#pragma unroll
  for (int m = 1; m < 64; m <<= 1) acc += __shfl_xor(acc, m);
  const int wave = threadIdx.x >> 6;
  const int lane = threadIdx.x & 63;
  if (lane == 0) red[wave] = acc;
  __syncthreads();
  if (threadIdx.x == 0) {
    float t = 0.0f;
#pragma unroll
    for (int w = 0; w < 16; ++w) t += red[w];
    out[0] = t / (float)kN;
  }
}

extern "C" void kernel_launch(void* const* d_in, const int* in_sizes, int n_in,
                              void* d_out, int out_size, void* d_ws, size_t ws_size,
                              hipStream_t stream) {
  const float* e1 = (const float*)d_in[0];
  const float* e2 = (const float*)d_in[1];
  float* out = (float*)d_out;

  // ws layout: [Zn bf16 tiled: N*D*2 = 4MB][s_sum: N*4][pos_sum: N*4] ~4.07MB
  unsigned short* zn = (unsigned short*)d_ws;
  float* s_sum   = (float*)((char*)d_ws + (size_t)kN * kD * 2);
  float* pos_sum = s_sum + kN;

  hipLaunchKernelGGL(k_normalize, dim3(kN / 4), dim3(256), 0, stream,
                     e1, e2, zn, s_sum);
  hipLaunchKernelGGL(k_simlse, dim3(32 * kBlkCol), dim3(512), 0, stream,
                     zn, s_sum, pos_sum);
  hipLaunchKernelGGL(k_final, dim3(1), dim3(1024), 0, stream,
                     s_sum, pos_sum, out);
}